// Round 16
// baseline (215.524 us; speedup 1.0000x reference)
//
#include <hip/hip_runtime.h>

// SparseMLP (grouped GEMM MoE): out = gelu_tanh(x @ w1^T) @ w2, per expert.
// E=64, CAP=64, H=1024, F=2048, fp32 in/out.
// R16: IN-FLIGHT BYTES. Cross-round evidence: delivered BW tracks aggregate
// outstanding load bytes per CU (R14 66KB->4.2, R15 98KB->5.1, R10 131KB->5.3,
// read-bench 200+KB->7.05 TB/s), not wave count alone. This round: 256-thread
// blocks, 64x64x64 tiles, LDS 32KB/block, launch_bounds(256,5) -> 5 blocks/CU
// (20 waves) with per-thread staging kept at 8x16B (pass1) -> ~164 KB/CU in
// flight. Template otherwise = R6: 2-deep prefetch, nt w-loads, regular x/h,
// nt out stores, T1 XCD swizzle, T2 LDS XOR swizzle, T4 counted barriers.

typedef __attribute__((ext_vector_type(8))) short short8;    // 8 bf16 = 4 VGPR
typedef __attribute__((ext_vector_type(4))) float f32x4;     // MFMA acc / ld
typedef __attribute__((ext_vector_type(8))) unsigned short ushort8;

#define NE   64
#define CAPT 64
#define HD   1024
#define FD   2048

// fp32 -> bf16 round-to-nearest-even
__device__ __forceinline__ unsigned short f2bf(float f) {
  union { float f; unsigned u; } v; v.f = f;
  unsigned r = v.u + 0x7FFFu + ((v.u >> 16) & 1u);
  return (unsigned short)(r >> 16);
}

// gelu_tanh(v) = v * sigmoid(2*0.79788456*(v + 0.044715 v^3))  (exact rewrite)
__device__ __forceinline__ float gelu_t(float v) {
  float u = 1.5957691216057308f * (v + 0.044715f * v * v * v);
  return v / (1.0f + __expf(-u));
}

// XOR swizzle (T2) for a [rows][64]-bf16 tile (row stride 128B).
__device__ __forceinline__ int swz(int row, int kbyte) {
  return row * 128 + (kbyte ^ ((row & 7) << 4));
}

__device__ __forceinline__ void cvt_wr4(unsigned char* dst, f32x4 v) {
  uint2 p;
  p.x = (unsigned)f2bf(v.x) | ((unsigned)f2bf(v.y) << 16);
  p.y = (unsigned)f2bf(v.z) | ((unsigned)f2bf(v.w) << 16);
  *(uint2*)dst = p;   // ds_write_b64
}

// Raw barrier with LDS-only drain (T4): outstanding GLOBAL loads stay in
// flight across the barrier; register deps produce counted vmcnt waits.
__device__ __forceinline__ void tile_barrier() {
  asm volatile("s_waitcnt lgkmcnt(0)" ::: "memory");
  __builtin_amdgcn_s_barrier();
  __builtin_amdgcn_sched_barrier(0);
}

// Bijective XCD swizzle (T1): same-expert blocks share an L2.
__device__ __forceinline__ int xcd_swz(int bid, int grid) {
  return (bid & 7) * (grid >> 3) + (bid >> 3);
}

#define TSZ (64 * 128)   // one [64][64]-bf16 tile, bytes (8 KB)

// ---------------------------------------------------------------- pass 1 ---
// C1[64,2048] = x_e[64,1024] @ w1_e[2048,1024]^T  (NT: both K-contiguous)
// grid = E*32 = 2048 blocks of 256 thr; tile 64x64x64; 4 waves (2x2),
// wave tile 32x32. LDS 32KB -> 5 blocks/CU at launch_bounds(256,5).
__global__ __launch_bounds__(256, 5)
void moe_pass1(const float* __restrict__ x, const float* __restrict__ w1,
               unsigned short* __restrict__ hb) {
  __shared__ __align__(16) unsigned char sA[2 * TSZ];   // 16 KB
  __shared__ __align__(16) unsigned char sB[2 * TSZ];   // 16 KB
  const int bid = xcd_swz(blockIdx.x, NE * 32);
  const int e = bid >> 5, nb = bid & 31;
  const int t = threadIdx.x, lane = t & 63, wid = t >> 6;
  const int wm = wid >> 1, wn = wid & 1;
  const int lr = lane & 15, lk16 = (lane >> 4) * 16;

  const float* xg  = x  + (size_t)e * CAPT * HD;
  const float* w1g = w1 + ((size_t)e * FD + (size_t)nb * 64) * HD;

  f32x4 acc[2][2] = {};

  // staging: 64 rows x 16 chunks (16B f32x4) = 1024 units; 4/thread each op.
  f32x4 ra[4], rb[4];
  auto loadT = [&](int k0) {
    #pragma unroll
    for (int i = 0; i < 4; ++i) {
      int u = t + i * 256;
      ra[i] = *(const f32x4*)(xg + (u >> 4) * HD + k0 + (u & 15) * 4);   // L2-reused
    }
    #pragma unroll
    for (int i = 0; i < 4; ++i) {
      int u = t + i * 256;
      rb[i] = __builtin_nontemporal_load(                                 // stream
          (const f32x4*)(w1g + (u >> 4) * HD + k0 + (u & 15) * 4));
    }
  };
  auto writeT = [&](unsigned char* a, unsigned char* b) {
    #pragma unroll
    for (int i = 0; i < 4; ++i) {
      int u = t + i * 256;
      cvt_wr4(a + swz(u >> 4, (u & 15) * 8), ra[i]);
    }
    #pragma unroll
    for (int i = 0; i < 4; ++i) {
      int u = t + i * 256;
      cvt_wr4(b + swz(u >> 4, (u & 15) * 8), rb[i]);
    }
  };

  const int NK = HD / 64;                      // 16 K-steps
  loadT(0);
  writeT(sA, sB);
  loadT(64);
  tile_barrier();

  int cur = 0;
  #pragma unroll 1
  for (int ks = 0; ks < NK; ++ks) {
    unsigned char* cA = sA + cur * TSZ;
    unsigned char* cB = sB + cur * TSZ;
    if (ks + 1 < NK) writeT(sA + (cur ^ 1) * TSZ, sB + (cur ^ 1) * TSZ);
    if (ks + 2 < NK) loadT((ks + 2) * 64);

    #pragma unroll
    for (int kk = 0; kk < 2; ++kk) {           // K=64 = 2 x 32
      short8 af[2], bfr[2];
      #pragma unroll
      for (int fm = 0; fm < 2; ++fm)
        af[fm] = *(const short8*)(cA + swz(wm * 32 + fm * 16 + lr, kk * 64 + lk16));
      #pragma unroll
      for (int fn = 0; fn < 2; ++fn)
        bfr[fn] = *(const short8*)(cB + swz(wn * 32 + fn * 16 + lr, kk * 64 + lk16));
      #pragma unroll
      for (int fm = 0; fm < 2; ++fm)
        #pragma unroll
        for (int fn = 0; fn < 2; ++fn)
          acc[fm][fn] = __builtin_amdgcn_mfma_f32_16x16x32_bf16(af[fm], bfr[fn], acc[fm][fn], 0, 0, 0);
    }
    tile_barrier();
    cur ^= 1;
  }

  // epilogue: gelu, cvt bf16, store h. C/D map: col=lane&15, row=(lane>>4)*4+j
  unsigned short* hp = hb + (size_t)e * CAPT * FD + nb * 64;
  #pragma unroll
  for (int fm = 0; fm < 2; ++fm)
    #pragma unroll
    for (int fn = 0; fn < 2; ++fn)
      #pragma unroll
      for (int j = 0; j < 4; ++j) {
        int m = wm * 32 + fm * 16 + (lane >> 4) * 4 + j;
        int f = wn * 32 + fn * 16 + lr;
        hp[(size_t)m * FD + f] = f2bf(gelu_t(acc[fm][fn][j]));
      }
}

// ---------------------------------------------------------------- pass 2 ---
// C2[64,1024] = h_e[64,2048](bf16) @ w2_e[2048,1024]  (NN: w2 transposed at
// stage time into LDS [n][k]). 256 thr, tile 64x64x64, 5 blocks/CU.
__global__ __launch_bounds__(256, 5)
void moe_pass2(const unsigned short* __restrict__ hb, const float* __restrict__ w2,
               float* __restrict__ out) {
  __shared__ __align__(16) unsigned char sA[2 * TSZ];   // 16 KB (h)
  __shared__ __align__(16) unsigned char sB[2 * TSZ];   // 16 KB ([n][k] w2)
  const int bid = xcd_swz(blockIdx.x, NE * 16);
  const int e = bid >> 4, nb = bid & 15;
  const int t = threadIdx.x, lane = t & 63, wid = t >> 6;
  const int wm = wid >> 1, wn = wid & 1;
  const int lr = lane & 15, lk16 = (lane >> 4) * 16;

  const unsigned short* hg = hb + (size_t)e * CAPT * FD;
  const float* w2g = w2 + (size_t)e * FD * HD + nb * 64;

  f32x4 acc[2][2] = {};

  const int bn = t & 63, bkg = t >> 6;   // B: lane owns col n, k-group of 16

  ushort8 rav[2];
  float rbv[16];
  auto loadT = [&](int f0) {
    #pragma unroll
    for (int i = 0; i < 2; ++i) {
      int u = t + i * 256;               // A: 512 ushort8 units, 2/thread
      rav[i] = *(const ushort8*)(hg + (size_t)(u >> 3) * FD + f0 + (u & 7) * 8);
    }
    #pragma unroll
    for (int j = 0; j < 16; ++j)
      rbv[j] = __builtin_nontemporal_load(                                 // stream
          w2g + (size_t)(f0 + bkg * 16 + j) * HD + bn);
  };
  auto writeT = [&](unsigned char* a, unsigned char* b) {
    #pragma unroll
    for (int i = 0; i < 2; ++i) {
      int u = t + i * 256;
      *(ushort8*)(a + swz(u >> 3, (u & 7) * 16)) = rav[i];   // ds_write_b128
    }
    #pragma unroll
    for (int i = 0; i < 4; ++i) {                      // transposed b64 writes
      uint2 p;
      p.x = (unsigned)f2bf(rbv[i * 4 + 0]) | ((unsigned)f2bf(rbv[i * 4 + 1]) << 16);
      p.y = (unsigned)f2bf(rbv[i * 4 + 2]) | ((unsigned)f2bf(rbv[i * 4 + 3]) << 16);
      *(uint2*)(b + swz(bn, bkg * 32 + i * 8)) = p;
    }
  };

  const int NK = FD / 64;                      // 32 K-steps
  loadT(0);
  writeT(sA, sB);
  loadT(64);
  tile_barrier();

  int cur = 0;
  #pragma unroll 1
  for (int ks = 0; ks < NK; ++ks) {
    unsigned char* cA = sA + cur * TSZ;
    unsigned char* cB = sB + cur * TSZ;
    if (ks + 1 < NK) writeT(sA + (cur ^ 1) * TSZ, sB + (cur ^ 1) * TSZ);
    if (ks + 2 < NK) loadT((ks + 2) * 64);

    #pragma unroll
    for (int kk = 0; kk < 2; ++kk) {
      short8 af[2], bfr[2];
      #pragma unroll
      for (int fm = 0; fm < 2; ++fm)
        af[fm] = *(const short8*)(cA + swz(wm * 32 + fm * 16 + lr, kk * 64 + lk16));
      #pragma unroll
      for (int fn = 0; fn < 2; ++fn)
        bfr[fn] = *(const short8*)(cB + swz(wn * 32 + fn * 16 + lr, kk * 64 + lk16));
      #pragma unroll
      for (int fm = 0; fm < 2; ++fm)
        #pragma unroll
        for (int fn = 0; fn < 2; ++fn)
          acc[fm][fn] = __builtin_amdgcn_mfma_f32_16x16x32_bf16(af[fm], bfr[fn], acc[fm][fn], 0, 0, 0);
    }
    tile_barrier();
    cur ^= 1;
  }

  float* op = out + (size_t)e * CAPT * HD + nb * 64;
  #pragma unroll
  for (int fm = 0; fm < 2; ++fm)
    #pragma unroll
    for (int fn = 0; fn < 2; ++fn)
      #pragma unroll
      for (int j = 0; j < 4; ++j) {
        int m = wm * 32 + fm * 16 + (lane >> 4) * 4 + j;
        int n = wn * 32 + fn * 16 + lr;
        __builtin_nontemporal_store(acc[fm][fn][j], op + (size_t)m * HD + n);
      }
}

extern "C" void kernel_launch(void* const* d_in, const int* in_sizes, int n_in,
                              void* d_out, int out_size, void* d_ws, size_t ws_size,
                              hipStream_t stream) {
  const float* x  = (const float*)d_in[0];
  const float* w1 = (const float*)d_in[1];
  const float* w2 = (const float*)d_in[2];
  float* out = (float*)d_out;
  unsigned short* hb = (unsigned short*)d_ws;   // h: E*CAP*F bf16 = 16.78 MB
  (void)in_sizes; (void)n_in; (void)out_size; (void)ws_size;

  moe_pass1<<<dim3(NE * 32), dim3(256), 0, stream>>>(x, w1, hb);
  moe_pass2<<<dim3(NE * 16), dim3(256), 0, stream>>>(hb, w2, out);
}

// Round 17
// 204.383 us; speedup vs baseline: 1.0545x; 1.0545x over previous
//
#include <hip/hip_runtime.h>

// SparseMLP (grouped GEMM MoE): out = gelu_tanh(x @ w1^T) @ w2, per expert.
// E=64, CAP=64, H=1024, F=2048, fp32 in/out. HBM-bound: ~1.09 GB moved.
// R17: RESTORE best-known configuration (R10, 204.8us). 16 rounds of
// structural variants (barrier semantics, prefetch depth, global_load_lds,
// tile geometry, occupancy 8-24 waves/CU) all land 205-235us; only cache
// policy (nt weight loads, R5) produced a real win. Effective BW ~5.35 TB/s
// vs 6.3-7.05 TB/s isolated ceilings -> within ~8% of the practical bound
// (~190us) for this 2-dispatch dependent mixed-stream workload.
// Config: pass1 BM=64 BN=64 BK=128 (512B-contiguous w1 wave-loads, NK=8);
// pass2 BM=64 BN=128 BK=64. Both: 2-deep register prefetch, nt w-loads,
// regular x/h loads + h stores (L2/L3 resident), nt out stores, T1 XCD
// swizzle, T2 LDS XOR swizzle, T4 counted-wait barriers (lgkm-only drain).

typedef __attribute__((ext_vector_type(8))) short short8;    // 8 bf16 = 4 VGPR
typedef __attribute__((ext_vector_type(4))) float f32x4;     // MFMA acc / ld
typedef __attribute__((ext_vector_type(8))) unsigned short ushort8;

#define NE   64
#define CAPT 64
#define HD   1024
#define FD   2048

// fp32 -> bf16 round-to-nearest-even
__device__ __forceinline__ unsigned short f2bf(float f) {
  union { float f; unsigned u; } v; v.f = f;
  unsigned r = v.u + 0x7FFFu + ((v.u >> 16) & 1u);
  return (unsigned short)(r >> 16);
}

// gelu_tanh(v) = v * sigmoid(2*0.79788456*(v + 0.044715 v^3))  (exact rewrite)
__device__ __forceinline__ float gelu_t(float v) {
  float u = 1.5957691216057308f * (v + 0.044715f * v * v * v);
  return v / (1.0f + __expf(-u));
}

// XOR swizzle (T2) for a [rows][64]-bf16 tile (row stride 128B): pass 2.
__device__ __forceinline__ int swz(int row, int kbyte) {
  return row * 128 + (kbyte ^ ((row & 7) << 4));
}
// XOR swizzle for a [rows][128]-bf16 tile (row stride 256B): pass 1 (BK=128).
__device__ __forceinline__ int swz2(int row, int kbyte) {
  return row * 256 + (kbyte ^ ((row & 7) << 4));
}

__device__ __forceinline__ void cvt_wr4(unsigned char* dst, f32x4 v) {
  uint2 p;
  p.x = (unsigned)f2bf(v.x) | ((unsigned)f2bf(v.y) << 16);
  p.y = (unsigned)f2bf(v.z) | ((unsigned)f2bf(v.w) << 16);
  *(uint2*)dst = p;   // ds_write_b64
}

// Raw barrier with LDS-only drain (T4): outstanding GLOBAL loads stay in
// flight across the barrier; register deps produce counted vmcnt waits.
__device__ __forceinline__ void tile_barrier() {
  asm volatile("s_waitcnt lgkmcnt(0)" ::: "memory");
  __builtin_amdgcn_s_barrier();
  __builtin_amdgcn_sched_barrier(0);
}

// Bijective XCD swizzle (T1): same-expert blocks share an L2.
__device__ __forceinline__ int xcd_swz(int bid, int grid) {
  return (bid & 7) * (grid >> 3) + (bid >> 3);
}

// ---------------------------------------------------------------- pass 1 ---
// C1[64,2048] = x_e[64,1024] @ w1_e[2048,1024]^T  (NT: both K-contiguous)
// grid = E*(F/64)=2048; tile BM=64 BN=64 BK=128; 8 waves (2x4), wave 32x16.
#define P1_TSZ (64 * 256)          // one [64][128]-bf16 buffer, bytes
__global__ __launch_bounds__(512, 4)
void moe_pass1(const float* __restrict__ x, const float* __restrict__ w1,
               unsigned short* __restrict__ hb) {
  __shared__ __align__(16) unsigned char sA[2 * P1_TSZ];   // 32 KB
  __shared__ __align__(16) unsigned char sB[2 * P1_TSZ];   // 32 KB
  const int bid = xcd_swz(blockIdx.x, NE * 32);
  const int e = bid >> 5, nb = bid & 31;
  const int t = threadIdx.x, lane = t & 63, wid = t >> 6;
  const int wm = wid >> 2, wn = wid & 3;
  const int lr = lane & 15, lk16 = (lane >> 4) * 16;

  const float* xg  = x  + (size_t)e * CAPT * HD;
  const float* w1g = w1 + ((size_t)e * FD + (size_t)nb * 64) * HD;

  f32x4 acc[2] = {};

  // Staging: tiles are 64 rows x 32 chunks(16B fp32). 2048 units, 4/thread.
  // u = t + i*512 -> row = u>>5, chunk = u&31. Per wave instr: 2 rows x 512B.
  f32x4 ra[4], rb[4];
  auto loadT = [&](int k0) {
    #pragma unroll
    for (int i = 0; i < 4; ++i) {
      int u = t + i * 512;
      ra[i] = *(const f32x4*)(xg + (u >> 5) * HD + k0 + (u & 31) * 4);
    }
    #pragma unroll
    for (int i = 0; i < 4; ++i) {
      int u = t + i * 512;
      rb[i] = __builtin_nontemporal_load(                    // single-use stream
          (const f32x4*)(w1g + (u >> 5) * HD + k0 + (u & 31) * 4));
    }
  };
  auto writeT = [&](unsigned char* a, unsigned char* b) {
    #pragma unroll
    for (int i = 0; i < 4; ++i) {
      int u = t + i * 512;
      cvt_wr4(a + swz2(u >> 5, (u & 31) * 8), ra[i]);
    }
    #pragma unroll
    for (int i = 0; i < 4; ++i) {
      int u = t + i * 512;
      cvt_wr4(b + swz2(u >> 5, (u & 31) * 8), rb[i]);
    }
  };

  const int NK = HD / 128;                                   // 8 K-steps
  loadT(0);
  writeT(sA, sB);
  loadT(128);
  tile_barrier();

  int cur = 0;
  #pragma unroll 1
  for (int ks = 0; ks < NK; ++ks) {
    unsigned char* cA = sA + cur * P1_TSZ;
    unsigned char* cB = sB + cur * P1_TSZ;
    if (ks + 1 < NK) writeT(sA + (cur ^ 1) * P1_TSZ, sB + (cur ^ 1) * P1_TSZ);
    if (ks + 2 < NK) loadT((ks + 2) * 128);

    #pragma unroll
    for (int kk = 0; kk < 4; ++kk) {                         // K=128 = 4x32
      short8 af0 = *(const short8*)(cA + swz2(wm * 32 + lr,      kk * 64 + lk16));
      short8 af1 = *(const short8*)(cA + swz2(wm * 32 + 16 + lr, kk * 64 + lk16));
      short8 bfr = *(const short8*)(cB + swz2(wn * 16 + lr,      kk * 64 + lk16));
      acc[0] = __builtin_amdgcn_mfma_f32_16x16x32_bf16(af0, bfr, acc[0], 0, 0, 0);
      acc[1] = __builtin_amdgcn_mfma_f32_16x16x32_bf16(af1, bfr, acc[1], 0, 0, 0);
    }
    tile_barrier();
    cur ^= 1;
  }

  // epilogue: gelu, cvt bf16, store h. C/D map: col=lane&15, row=(lane>>4)*4+j
  unsigned short* hp = hb + (size_t)e * CAPT * FD + nb * 64;
  #pragma unroll
  for (int fm = 0; fm < 2; ++fm)
    #pragma unroll
    for (int j = 0; j < 4; ++j) {
      int m = wm * 32 + fm * 16 + (lane >> 4) * 4 + j;
      int f = wn * 16 + lr;
      hp[(size_t)m * FD + f] = f2bf(gelu_t(acc[fm][j]));
    }
}

#define A_SZ (64 * 128)
#define B_SZ (128 * 128)

// ---------------------------------------------------------------- pass 2 ---
// C2[64,1024] = h_e[64,2048](bf16) @ w2_e[2048,1024]  (NN: w2 transposed at
// stage time into LDS [n][k]). R6 known-good body, 2-deep prefetch.
__global__ __launch_bounds__(512, 4)
void moe_pass2(const unsigned short* __restrict__ hb, const float* __restrict__ w2,
               float* __restrict__ out) {
  __shared__ __align__(16) unsigned char sA[2 * A_SZ];
  __shared__ __align__(16) unsigned char sB[2 * B_SZ];
  const int bid = xcd_swz(blockIdx.x, NE * 8);
  const int e = bid >> 3, nb = bid & 7;
  const int t = threadIdx.x, lane = t & 63, wid = t >> 6;
  const int wm = wid >> 2, wn = wid & 3;
  const int lr = lane & 15, lkb = (lane >> 4) * 16;

  const unsigned short* hg = hb + (size_t)e * CAPT * FD;
  const float* w2g = w2 + (size_t)e * FD * HD + nb * 128;

  f32x4 acc[2][2] = {};

  const int ar = t >> 3, ac = t & 7;     // A: 512 units of 8 bf16, 1/thread
  const int bn = t & 127, bkg = t >> 7;  // B: lane owns col n, k-group of 16

  ushort8 rav;
  float rbv[16];
  auto loadT = [&](int f0) {
    rav = *(const ushort8*)(hg + (size_t)ar * FD + f0 + ac * 8);          // L2/L3-warm
    #pragma unroll
    for (int i = 0; i < 4; ++i)
      #pragma unroll
      for (int j = 0; j < 4; ++j)
        rbv[i * 4 + j] = __builtin_nontemporal_load(                       // stream
            w2g + (size_t)(f0 + bkg * 16 + i * 4 + j) * HD + bn);
  };
  auto writeT = [&](unsigned char* a, unsigned char* b) {
    *(ushort8*)(a + swz(ar, ac * 16)) = rav;           // ds_write_b128
    #pragma unroll
    for (int i = 0; i < 4; ++i) {                      // transposed b64 writes
      uint2 p;
      p.x = (unsigned)f2bf(rbv[i * 4 + 0]) | ((unsigned)f2bf(rbv[i * 4 + 1]) << 16);
      p.y = (unsigned)f2bf(rbv[i * 4 + 2]) | ((unsigned)f2bf(rbv[i * 4 + 3]) << 16);
      *(uint2*)(b + swz(bn, (bkg * 16 + i * 4) * 2)) = p;
    }
  };

  const int NK = FD / 64;
  loadT(0);
  writeT(sA, sB);
  loadT(64);
  tile_barrier();

  int cur = 0;
  #pragma unroll 1
  for (int ks = 0; ks < NK; ++ks) {
    unsigned char* cA = sA + cur * A_SZ;
    unsigned char* cB = sB + cur * B_SZ;
    if (ks + 1 < NK) writeT(sA + (cur ^ 1) * A_SZ, sB + (cur ^ 1) * B_SZ);
    if (ks + 2 < NK) loadT((ks + 2) * 64);

    short8 af[2][2], bf[2][2];
    #pragma unroll
    for (int fm = 0; fm < 2; ++fm)
      #pragma unroll
      for (int kk = 0; kk < 2; ++kk)
        af[fm][kk] = *(const short8*)(cA + swz(wm * 32 + fm * 16 + lr, kk * 64 + lkb));
    #pragma unroll
    for (int fn = 0; fn < 2; ++fn)
      #pragma unroll
      for (int kk = 0; kk < 2; ++kk)
        bf[fn][kk] = *(const short8*)(cB + swz(wn * 32 + fn * 16 + lr, kk * 64 + lkb));
    #pragma unroll
    for (int fm = 0; fm < 2; ++fm)
      #pragma unroll
      for (int fn = 0; fn < 2; ++fn) {
        acc[fm][fn] = __builtin_amdgcn_mfma_f32_16x16x32_bf16(af[fm][0], bf[fn][0], acc[fm][fn], 0, 0, 0);
        acc[fm][fn] = __builtin_amdgcn_mfma_f32_16x16x32_bf16(af[fm][1], bf[fn][1], acc[fm][fn], 0, 0, 0);
      }
    tile_barrier();
    cur ^= 1;
  }

  float* op = out + (size_t)e * CAPT * HD + nb * 128;
  #pragma unroll
  for (int fm = 0; fm < 2; ++fm)
    #pragma unroll
    for (int fn = 0; fn < 2; ++fn)
      #pragma unroll
      for (int j = 0; j < 4; ++j) {
        int m = wm * 32 + fm * 16 + (lane >> 4) * 4 + j;
        int n = wn * 32 + fn * 16 + lr;
        __builtin_nontemporal_store(acc[fm][fn][j], op + (size_t)m * HD + n);
      }
}

extern "C" void kernel_launch(void* const* d_in, const int* in_sizes, int n_in,
                              void* d_out, int out_size, void* d_ws, size_t ws_size,
                              hipStream_t stream) {
  const float* x  = (const float*)d_in[0];
  const float* w1 = (const float*)d_in[1];
  const float* w2 = (const float*)d_in[2];
  float* out = (float*)d_out;
  unsigned short* hb = (unsigned short*)d_ws;   // h: E*CAP*F bf16 = 16.78 MB
  (void)in_sizes; (void)n_in; (void)out_size; (void)ws_size;

  moe_pass1<<<dim3(NE * (FD / 64)), dim3(512), 0, stream>>>(x, w1, hb);
  moe_pass2<<<dim3(NE * (HD / 128)), dim3(512), 0, stream>>>(hb, w2, out);
}